// Round 1
// baseline (135.060 us; speedup 1.0000x reference)
//
#include <hip/hip_runtime.h>
#include <cstdint>
#include <cstddef>

typedef __attribute__((ext_vector_type(8))) __bf16 bf16x8;
typedef __attribute__((ext_vector_type(4))) float f32x4;

#define MFMA16(a, b, c) __builtin_amdgcn_mfma_f32_16x16x32_bf16((a), (b), (c), 0, 0, 0)

__device__ __forceinline__ float fast_tanh(float z) {
    float e = __expf(2.0f * z);
    return 1.0f - 2.0f * __builtin_amdgcn_rcpf(e + 1.0f);
}
__device__ __forceinline__ float fast_sigmoid(float z) {
    return __builtin_amdgcn_rcpf(1.0f + __expf(-z));
}

__device__ __forceinline__ unsigned pk2(float a, float b) {
    union { __bf16 h[2]; unsigned u; } p;
    p.h[0] = (__bf16)a;
    p.h[1] = (__bf16)b;
    return p.u;
}

// weight A-fragment: lane holds row `row`, k = k0..k0+7 (contiguous in row-major W[64][64])
__device__ __forceinline__ bf16x8 ldwfrag(const float* __restrict__ W, int row, int k0) {
    const float4 a = *(const float4*)(W + row * 64 + k0);
    const float4 b = *(const float4*)(W + row * 64 + k0 + 4);
    bf16x8 f;
    f[0] = (__bf16)a.x; f[1] = (__bf16)a.y; f[2] = (__bf16)a.z; f[3] = (__bf16)a.w;
    f[4] = (__bf16)b.x; f[5] = (__bf16)b.y; f[6] = (__bf16)b.z; f[7] = (__bf16)b.w;
    return f;
}

// Cox-de Boor, order 3, 12 knots -> 8 basis funcs. Exact replication of the
// reference recurrence (incl. >=/< on order-0 and zero basis outside knot span).
__device__ __forceinline__ void bspl8(float x, const float* kn, float* B) {
    float b[11];
#pragma unroll
    for (int m = 0; m < 11; ++m)
        b[m] = (x >= kn[m] && x < kn[m + 1]) ? 1.0f : 0.0f;
#pragma unroll
    for (int d = 1; d <= 3; ++d) {
#pragma unroll
        for (int m = 0; m + d < 11; ++m) {
            float lf = (x - kn[m]) / (kn[m + d] - kn[m]) * b[m];
            float rt = (kn[m + d + 1] - x) / (kn[m + d + 1] - kn[m + 1]) * b[m + 1];
            b[m] = lf + rt;
        }
    }
#pragma unroll
    for (int m = 0; m < 8; ++m) B[m] = b[m];
}

// One block = 16 batch samples through all 256 steps of both RNN layers + KAN.
// 4 waves; wave wv owns hidden rows [16*wv, 16*wv+16).
// Layer-skewed: iteration t computes h1[t] and h2[t-1] -> ONE barrier/step.
__global__ __launch_bounds__(256, 1) void rnn_kan_fused(
    const float* __restrict__ x,
    const float* __restrict__ wih0, const float* __restrict__ whh0,
    const float* __restrict__ bih0, const float* __restrict__ bhh0,
    const float* __restrict__ wih1, const float* __restrict__ whh1,
    const float* __restrict__ bih1, const float* __restrict__ bhh1,
    const float* __restrict__ grid0, const float* __restrict__ coef0,
    const float* __restrict__ sb0, const float* __restrict__ sp0,
    const float* __restrict__ grid1, const float* __restrict__ coef1,
    const float* __restrict__ sb1, const float* __restrict__ sp1,
    float* __restrict__ out)
{
    __shared__ __align__(16) float s_x[4][1024];          // x ring: 4 slots x (16 samples x 64 f)
    __shared__ __align__(16) unsigned char s_h1[2][2048]; // h1 bf16, double-buffered, swizzled
    __shared__ __align__(16) unsigned char s_h2[2][2048]; // h2 bf16
    __shared__ __align__(16) float s_hf[16][68];          // final h2 fp32 (padded)
    __shared__ __align__(16) float s_bas[1024][12];       // KAN0 basis[8] + silu at [8]
    __shared__ __align__(16) float s_e[16][17];           // KAN1 edge values

    const int tid  = threadIdx.x;
    const int wv   = tid >> 6;
    const int lane = tid & 63;
    const int sc   = lane & 15;   // MFMA col (= sample) index
    const int gr   = lane >> 4;   // MFMA 16-lane group
    const int s0   = blockIdx.x << 4;

    // ---- weights -> A-fragments (row = 16*wv + sc, k = 32*kt + 8*gr + e)
    const int wrow = 16 * wv + sc;
    const int kofs = 8 * gr;
    bf16x8 fWih0[2], fWhh0[2], fWih1[2], fWhh1[2];
#pragma unroll
    for (int kt = 0; kt < 2; ++kt) {
        fWih0[kt] = ldwfrag(wih0, wrow, 32 * kt + kofs);
        fWhh0[kt] = ldwfrag(whh0, wrow, 32 * kt + kofs);
        fWih1[kt] = ldwfrag(wih1, wrow, 32 * kt + kofs);
        fWhh1[kt] = ldwfrag(whh1, wrow, 32 * kt + kofs);
    }
    // biases for this lane's 4 C-rows: h = 16*wv + 4*gr + i
    f32x4 b0v, b1v;
#pragma unroll
    for (int i = 0; i < 4; ++i) {
        const int h = 16 * wv + 4 * gr + i;
        b0v[i] = bih0[h] + bhh0[h];
        b1v[i] = bih1[h] + bhh1[h];
    }

    // ---- x staging plumbing: wave wv stages samples 4wv..4wv+3 (1KB) per step.
    // LDS dest is linear (global_load_lds), so the bank-swizzle is applied by
    // permuting the per-lane GLOBAL source chunk: chunk stored at block b holds
    // logical chunk b ^ (s&7).
    const int gs = 4 * wv + gr;                 // sample this lane stages
    const int gc = (lane & 15) ^ (gs & 7);      // swizzled 16B chunk it fetches
    const float* gsrc = x + (size_t)(s0 + gs) * 16384 + gc * 4;
    char* ldsx = (char*)(&s_x[0][0]);           // slot n at +4096*n, wave seg at +1024*wv

    // ---- LDS h-buffer byte offsets (XOR-swizzle on byte bits 4..6)
    const unsigned swz  = (unsigned)(sc & 7) << 4;
    const unsigned offW  = sc * 128 + (((unsigned)(32 * wv + 8 * gr)) ^ swz); // C write (b64)
    const unsigned offR0 = sc * 128 + (((unsigned)(16 * gr)) ^ swz);          // B-frag kt=0 (b128)
    const unsigned offR1 = sc * 128 + (((unsigned)(64 + 16 * gr)) ^ swz);     // B-frag kt=1
    unsigned offX[4];
#pragma unroll
    for (int kt = 0; kt < 2; ++kt)
#pragma unroll
        for (int h = 0; h < 2; ++h)
            offX[2 * kt + h] = sc * 256 + 16 * ((unsigned)(8 * kt + 2 * gr + h) ^ (unsigned)(sc & 7));

    // ---- prologue: stage x[0..2]
#pragma unroll
    for (int t = 0; t < 3; ++t) {
        __builtin_amdgcn_global_load_lds(
            (const __attribute__((address_space(1))) void*)(gsrc + t * 64),
            (__attribute__((address_space(3))) void*)(ldsx + t * 4096 + wv * 1024),
            16, 0, 0);
    }
    asm volatile("s_waitcnt vmcnt(2)" ::: "memory"); // x[0] landed (2 newer in flight)
    __builtin_amdgcn_s_barrier();
    asm volatile("" ::: "memory");

    bf16x8 h1f[2], h2f[2];
    {
        bf16x8 zf;
#pragma unroll
        for (int e = 0; e < 8; ++e) zf[e] = (__bf16)0.0f;
        h1f[0] = zf; h1f[1] = zf; h2f[0] = zf; h2f[1] = zf;
    }

    // xw[0] = b0 + Wih0 @ x[0]
    f32x4 xw_cur = b0v;
    {
        const char* xb = (const char*)(&s_x[0][0]);
#pragma unroll
        for (int kt = 0; kt < 2; ++kt) {
            const float4 q0 = *(const float4*)(xb + offX[2 * kt + 0]);
            const float4 q1 = *(const float4*)(xb + offX[2 * kt + 1]);
            bf16x8 xa;
            xa[0] = (__bf16)q0.x; xa[1] = (__bf16)q0.y; xa[2] = (__bf16)q0.z; xa[3] = (__bf16)q0.w;
            xa[4] = (__bf16)q1.x; xa[5] = (__bf16)q1.y; xa[6] = (__bf16)q1.z; xa[7] = (__bf16)q1.w;
            xw_cur = MFMA16(fWih0[kt], xa, xw_cur);
        }
    }

    // ---- main recurrence
    for (int t = 0; t < 256; ++t) {
        const int par = t & 1;
        {   // prefetch x[t+3] (clamped; keeps the vmcnt(2) discipline uniform)
            const int ts = (t + 3 > 255) ? 255 : t + 3;
            __builtin_amdgcn_global_load_lds(
                (const __attribute__((address_space(1))) void*)(gsrc + ts * 64),
                (__attribute__((address_space(3))) void*)(ldsx + ((t + 3) & 3) * 4096 + wv * 1024),
                16, 0, 0);
        }
        // h1[t] = tanh(xw[t] + Whh0 @ h1[t-1])
        f32x4 z1 = xw_cur;
        z1 = MFMA16(fWhh0[0], h1f[0], z1);
        z1 = MFMA16(fWhh0[1], h1f[1], z1);
        // h2[t-1] = tanh(b1 + Wih1 @ h1[t-1] + Whh1 @ h2[t-2])   (garbage at t=0, not written)
        f32x4 z2 = b1v;
        z2 = MFMA16(fWih1[0], h1f[0], z2);
        z2 = MFMA16(fWih1[1], h1f[1], z2);
        z2 = MFMA16(fWhh1[0], h2f[0], z2);
        z2 = MFMA16(fWhh1[1], h2f[1], z2);

        float v1[4], v2[4];
#pragma unroll
        for (int i = 0; i < 4; ++i) v1[i] = fast_tanh(z1[i]);
#pragma unroll
        for (int i = 0; i < 4; ++i) v2[i] = fast_tanh(z2[i]);

        uint2 pw1; pw1.x = pk2(v1[0], v1[1]); pw1.y = pk2(v1[2], v1[3]);
        *(uint2*)((char*)(&s_h1[par][0]) + offW) = pw1;
        if (t > 0) {
            uint2 pw2; pw2.x = pk2(v2[0], v2[1]); pw2.y = pk2(v2[2], v2[3]);
            *(uint2*)((char*)(&s_h2[par][0]) + offW) = pw2;
        }

        // counted vmcnt (NOT 0: keep 2 prefetches in flight) + raw barrier
        asm volatile("s_waitcnt vmcnt(2) lgkmcnt(0)" ::: "memory");
        __builtin_amdgcn_s_barrier();
        asm volatile("" ::: "memory");

        h1f[0] = *(const bf16x8*)((const char*)(&s_h1[par][0]) + offR0);
        h1f[1] = *(const bf16x8*)((const char*)(&s_h1[par][0]) + offR1);
        if (t > 0) {
            h2f[0] = *(const bf16x8*)((const char*)(&s_h2[par][0]) + offR0);
            h2f[1] = *(const bf16x8*)((const char*)(&s_h2[par][0]) + offR1);
        }

        {   // xw[t+1] = b0 + Wih0 @ x[t+1]   (off critical path)
            const char* xb = (const char*)(&s_x[(t + 1) & 3][0]);
            f32x4 acc = b0v;
#pragma unroll
            for (int kt = 0; kt < 2; ++kt) {
                const float4 q0 = *(const float4*)(xb + offX[2 * kt + 0]);
                const float4 q1 = *(const float4*)(xb + offX[2 * kt + 1]);
                bf16x8 xa;
                xa[0] = (__bf16)q0.x; xa[1] = (__bf16)q0.y; xa[2] = (__bf16)q0.z; xa[3] = (__bf16)q0.w;
                xa[4] = (__bf16)q1.x; xa[5] = (__bf16)q1.y; xa[6] = (__bf16)q1.z; xa[7] = (__bf16)q1.w;
                acc = MFMA16(fWih0[kt], xa, acc);
            }
            xw_cur = acc;
        }
    }

    // ---- final h2[255] = tanh(b1 + Wih1 @ h1[255] + Whh1 @ h2[254]) -> fp32 LDS for KAN
    {
        f32x4 z2 = b1v;
        z2 = MFMA16(fWih1[0], h1f[0], z2);
        z2 = MFMA16(fWih1[1], h1f[1], z2);
        z2 = MFMA16(fWhh1[0], h2f[0], z2);
        z2 = MFMA16(fWhh1[1], h2f[1], z2);
        f32x4 hv;
#pragma unroll
        for (int i = 0; i < 4; ++i) hv[i] = fast_tanh(z2[i]);
        *(f32x4*)(&s_hf[sc][16 * wv + 4 * gr]) = hv;
    }
    __syncthreads();

    // ---- KAN epilogue
    float kn0[12], kn1[12];
#pragma unroll
    for (int m = 0; m < 12; ++m) { kn0[m] = grid0[m]; kn1[m] = grid1[m]; }

    // K1: basis + silu for all 1024 (i, s) pairs
    for (int q = tid; q < 1024; q += 256) {
        const int i = q >> 4, s = q & 15;
        const float v = s_hf[s][i];
        float B[8];
        bspl8(v, kn0, B);
        *(float4*)(&s_bas[q][0]) = make_float4(B[0], B[1], B[2], B[3]);
        *(float4*)(&s_bas[q][4]) = make_float4(B[4], B[5], B[6], B[7]);
        s_bas[q][8] = v * fast_sigmoid(v);
    }
    __syncthreads();

    // K2: KAN0 out[s][o]; K3: KAN1 edge for (s,o)
    {
        const int s = tid >> 4, o = tid & 15;
        float acc = 0.0f;
        for (int i = 0; i < 64; ++i) {
            const int q = (i << 4) + s;
            const float4 B0 = *(const float4*)(&s_bas[q][0]);
            const float4 B1 = *(const float4*)(&s_bas[q][4]);
            const float sil = s_bas[q][8];
            const float* cp = coef0 + i * 128 + o * 8;
            const float4 c0 = *(const float4*)cp;
            const float4 c1 = *(const float4*)(cp + 4);
            const float spl = B0.x * c0.x + B0.y * c0.y + B0.z * c0.z + B0.w * c0.w +
                              B1.x * c1.x + B1.y * c1.y + B1.z * c1.z + B1.w * c1.w;
            acc += sil * sb0[(i << 4) + o] + sp0[(i << 4) + o] * spl;
        }
        float B[8];
        bspl8(acc, kn1, B);
        const float* cp = coef1 + o * 8;
        float spl = 0.0f;
#pragma unroll
        for (int k = 0; k < 8; ++k) spl += B[k] * cp[k];
        s_e[s][o] = (acc * fast_sigmoid(acc)) * sb1[o] + sp1[o] * spl;
    }
    __syncthreads();

    // K4: reduce 16 edges per sample, sigmoid, store
    if (tid < 16) {
        float sum = 0.0f;
#pragma unroll
        for (int o = 0; o < 16; ++o) sum += s_e[tid][o];
        out[s0 + tid] = fast_sigmoid(sum);
    }
}

extern "C" void kernel_launch(void* const* d_in, const int* in_sizes, int n_in,
                              void* d_out, int out_size, void* d_ws, size_t ws_size,
                              hipStream_t stream) {
    (void)n_in; (void)out_size; (void)d_ws; (void)ws_size;
    const int B = in_sizes[0] / (256 * 64);   // 2048
    const int grid = B / 16;                  // 128 blocks of 16 samples
    rnn_kan_fused<<<dim3(grid), dim3(256), 0, stream>>>(
        (const float*)d_in[0],
        (const float*)d_in[1], (const float*)d_in[2], (const float*)d_in[3], (const float*)d_in[4],
        (const float*)d_in[5], (const float*)d_in[6], (const float*)d_in[7], (const float*)d_in[8],
        (const float*)d_in[9], (const float*)d_in[10], (const float*)d_in[11], (const float*)d_in[12],
        (const float*)d_in[13], (const float*)d_in[14], (const float*)d_in[15], (const float*)d_in[16],
        (float*)d_out);
}